// Round 7
// baseline (281.065 us; speedup 1.0000x reference)
//
#include <hip/hip_runtime.h>
#include <hip/hip_bf16.h>
#include <stdint.h>

#define TOKENS 8192
#define IN_F   4096
#define OUT_F  4096
#define GROUP  128

typedef __attribute__((ext_vector_type(8))) short short8;
typedef __attribute__((ext_vector_type(4))) float f32x4;

// ---------------------------------------------------------------------------
// Kernel 1: convert x fp32 -> bf16 (workspace). 8 floats / thread-item.
// ---------------------------------------------------------------------------
__global__ void k_convert_x(const float* __restrict__ x,
                            __hip_bfloat16* __restrict__ xb) {
  const int64_t total = (int64_t)TOKENS * IN_F / 8;
  const int64_t stride = (int64_t)gridDim.x * blockDim.x;
  for (int64_t i = (int64_t)blockIdx.x * blockDim.x + threadIdx.x; i < total;
       i += stride) {
    const float4* p = reinterpret_cast<const float4*>(x) + i * 2;
    float4 a = p[0];
    float4 b = p[1];
    union {
      short8 v;
      __hip_bfloat16 h[8];
    } r;
    r.h[0] = __float2bfloat16(a.x);
    r.h[1] = __float2bfloat16(a.y);
    r.h[2] = __float2bfloat16(a.z);
    r.h[3] = __float2bfloat16(a.w);
    r.h[4] = __float2bfloat16(b.x);
    r.h[5] = __float2bfloat16(b.y);
    r.h[6] = __float2bfloat16(b.z);
    r.h[7] = __float2bfloat16(b.w);
    reinterpret_cast<short8*>(xb)[i] = r.v;
  }
}

// ---------------------------------------------------------------------------
// Kernel 2: dequantize qweight -> W^T bf16 [OUT_F][IN_F] (workspace).
// ---------------------------------------------------------------------------
__global__ void k_dequant(const int* __restrict__ qweight,
                          const int* __restrict__ qzeros,
                          const float* __restrict__ scales,
                          __hip_bfloat16* __restrict__ wt) {
  __shared__ __align__(16) __hip_bfloat16 sW[256][72];  // [n][k], +8 pad
  const int nt = blockIdx.x & 15;   // 16 n-tiles
  const int kt = blockIdx.x >> 4;   // 64 k-tiles
  const int n0 = nt * 256;
  const int k0 = kt * 64;           // multiple of 64 -> single group
  const int g = k0 / GROUP;
  const int t = threadIdx.x;
  const int n = n0 + t;

  const float s = scales[(size_t)g * OUT_F + n];
  const unsigned zw =
      ((const unsigned*)qzeros)[(size_t)g * (OUT_F / 8) + (n >> 3)];
  const float z = (float)((zw >> ((n & 7) * 4)) & 15u);
  const float sz = s * z;
  const int kw0 = k0 >> 3;
#pragma unroll
  for (int kw = 0; kw < 8; ++kw) {
    const unsigned w = ((const unsigned*)qweight)[(size_t)(kw0 + kw) * OUT_F + n];
#pragma unroll
    for (int j = 0; j < 8; ++j) {
      const float q = (float)((w >> (4 * j)) & 15u);
      sW[t][kw * 8 + j] = __float2bfloat16(s * q - sz);
    }
  }
  __syncthreads();
#pragma unroll
  for (int pass = 0; pass < 8; ++pass) {
    const int row = pass * 32 + (t >> 3);
    const int kc = t & 7;
    short8 v = *reinterpret_cast<const short8*>(&sW[row][kc * 8]);
    *reinterpret_cast<short8*>(wt + (size_t)(n0 + row) * IN_F + k0 + kc * 8) = v;
  }
}

// ---------------------------------------------------------------------------
// Kernel 3: 256x256 bf16 MFMA GEMM, 4-phase half-tile schedule.
// 512 threads = 8 waves (2M x 4N), BK=64, 2x64KiB LDS dbuf.
// Round-6 change: coarsen 8 quarter-phases -> 4 half-phases (32 MFMA/window)
// and drop pre-barriers except at the two vmcnt(4) drain points. Barriers
// 16 -> 6 per 2-K-tile iteration. WAR matrix: every STAGE is >=1 POST
// barrier after the overwritten region's last ds_read; every window read
// of a freshly-staged tile is after that tile's vmcnt drain + barrier.
// vmcnt(4) sits BEFORE the phase's own stages -> drains exactly the 8
// oldest loads (the tile read in this phase's window).
// ---------------------------------------------------------------------------
__device__ inline void gload_lds16(const void* g, void* l) {
  __builtin_amdgcn_global_load_lds(
      (const __attribute__((address_space(1))) void*)g,
      (__attribute__((address_space(3))) void*)l, 16, 0, 0);
}

// buf: 0/1, matsel: 0=A 1=B, half: 0/1 (rows half*128..+127), tile: k-tile
#define STAGE(buf, matsel, half, tile)                                        \
  do {                                                                        \
    const char* gb_ = (matsel) ? Bg : Ag;                                     \
    const int lm_ = (buf)*65536 + (matsel)*32768 + (half)*16384;              \
    _Pragma("unroll") for (int r_ = 0; r_ < 2; ++r_) {                        \
      gload_lds16(gb_ + (size_t)(half)*1048576 + goff[r_] +                   \
                      (size_t)(tile)*128,                                     \
                  smem + lm_ + ldsoff[r_]);                                   \
    }                                                                         \
  } while (0)

// A-frag read: m-half mh rows mh*128 + wr*64 + mfl*16 + fr -> dst[4][2]
#define READ_A(buf, mh, dst)                                                  \
  do {                                                                        \
    _Pragma("unroll") for (int mfl_ = 0; mfl_ < 4; ++mfl_) {                  \
      const int row_ = (mh)*128 + wr * 64 + mfl_ * 16 + fr;                   \
      const char* p_ = smem + (buf)*65536 + row_ * 128;                       \
      dst[mfl_][0] = *reinterpret_cast<const short8*>(p_ + csw0);             \
      dst[mfl_][1] = *reinterpret_cast<const short8*>(p_ + csw1);             \
    }                                                                         \
  } while (0)

// B-frag read: this wave's 64 n-rows (wc*64..+63) -> dst[4][2]
#define READ_B(buf, dst)                                                      \
  do {                                                                        \
    _Pragma("unroll") for (int nfl_ = 0; nfl_ < 4; ++nfl_) {                  \
      const int row_ = wc * 64 + nfl_ * 16 + fr;                              \
      const char* p_ = smem + (buf)*65536 + 32768 + row_ * 128;               \
      dst[nfl_][0] = *reinterpret_cast<const short8*>(p_ + csw0);             \
      dst[nfl_][1] = *reinterpret_cast<const short8*>(p_ + csw1);             \
    }                                                                         \
  } while (0)

// 32 MFMA: m-half mh x full n-width, K=64 (2 kk-steps)
#define MMA_H(aset, bset, mh)                                                 \
  do {                                                                        \
    _Pragma("unroll") for (int mfl_ = 0; mfl_ < 4; ++mfl_)                    \
        _Pragma("unroll") for (int nfl_ = 0; nfl_ < 4; ++nfl_) {              \
      const int mf_ = (mh)*4 + mfl_;                                          \
      acc[mf_][nfl_] = __builtin_amdgcn_mfma_f32_16x16x32_bf16(               \
          aset[mfl_][0], bset[nfl_][0], acc[mf_][nfl_], 0, 0, 0);             \
      acc[mf_][nfl_] = __builtin_amdgcn_mfma_f32_16x16x32_bf16(               \
          aset[mfl_][1], bset[nfl_][1], acc[mf_][nfl_], 0, 0, 0);             \
    }                                                                         \
  } while (0)

#define WIN_OPEN()                                                            \
  asm volatile("s_waitcnt lgkmcnt(0)" ::: "memory");                          \
  __builtin_amdgcn_sched_barrier(0);                                          \
  __builtin_amdgcn_s_setprio(1)

#define WIN_CLOSE()                                                           \
  __builtin_amdgcn_s_setprio(0);                                              \
  __builtin_amdgcn_sched_barrier(0);                                          \
  __builtin_amdgcn_s_barrier()

__global__ __launch_bounds__(512, 2) void k_gemm256(
    const __hip_bfloat16* __restrict__ xb,  // [TOKENS][IN_F]
    const __hip_bfloat16* __restrict__ wt,  // [OUT_F][IN_F]
    const float* __restrict__ bias,         // [OUT_F]
    float* __restrict__ out) {              // [TOKENS][OUT_F]
  extern __shared__ __align__(16) char smem[];  // 131072 B

  // 2D XCD chunking (bijective): XCD x gets 2bm x 16bn per round.
  const int bidx = blockIdx.x;
  const int xcd = bidx & 7;
  const int slot = bidx >> 3;          // 0..63
  const int rnd = slot >> 5;           // 0/1
  const int jj = slot & 31;
  const int bm = rnd * 16 + xcd * 2 + (jj >> 4);  // 0..31
  const int bn = jj & 15;                          // 0..15
  const int m0 = bm * 256;
  const int n0 = bn * 256;

  const int t = threadIdx.x;
  const int lane = t & 63;
  const int wid = t >> 6;       // 8 waves
  const int wr = wid >> 2;      // 2 (M): 64-row sub-block within m-half
  const int wc = wid & 3;       // 4 (N)
  const int fr = lane & 15;
  const int hq = lane >> 4;     // 0..3, k-quarter

  // swizzled ds_read chunk byte offsets (row&7 == fr&7 for all frag rows)
  const int csw0 = ((hq ^ (fr & 7))) * 16;        // kk=0
  const int csw1 = ((hq ^ (fr & 7)) ^ 4) * 16;    // kk=1

  // staging per-thread constants: round r covers chunk c = r*512 + t
  int goff[2], ldsoff[2];
#pragma unroll
  for (int r = 0; r < 2; ++r) {
    const int srow = r * 64 + wid * 8 + (lane >> 3);        // 0..127
    const int schunk = (lane & 7) ^ (srow & 7);             // inverse swizzle
    goff[r] = srow * (IN_F * 2) + schunk * 16;
    ldsoff[r] = (r * 512 + wid * 64) * 16;                  // wave-uniform
  }

  const char* Ag = (const char*)(xb + (size_t)m0 * IN_F);
  const char* Bg = (const char*)(wt + (size_t)n0 * IN_F);

  f32x4 acc[8][4];
#pragma unroll
  for (int i = 0; i < 8; ++i)
#pragma unroll
    for (int j2 = 0; j2 < 4; ++j2) acc[i][j2] = (f32x4){0.f, 0.f, 0.f, 0.f};

  short8 aX[4][2], aY[4][2];  // A frags: mh0 / mh1
  short8 bX[4][2], bY[4][2];  // B frags: even tile / odd tile

  // ---- prologue: stage tile0 (buf0) then tile1 (buf1); drain tile0.
  STAGE(0, 0, 0, 0);
  STAGE(0, 1, 0, 0);
  STAGE(0, 0, 1, 0);
  STAGE(0, 1, 1, 0);
  STAGE(1, 0, 0, 1);
  STAGE(1, 1, 0, 1);
  STAGE(1, 0, 1, 1);
  STAGE(1, 1, 1, 1);
  asm volatile("s_waitcnt vmcnt(8)" ::: "memory");  // tile0 landed
  __builtin_amdgcn_s_barrier();
  READ_A(0, 0, aX);  // T0 mh0 operands (drained by P1's lgkmcnt)
  READ_B(0, bX);     // B(T0)

  // ---- main loop: tiles T=2it (buf0), T+1 (buf1); 4 half-tile phases.
  for (int it = 0; it < IN_F / 128; ++it) {
    const int T = 2 * it;
    const int P0 = (T + 2) & 63;
    const int P1t = (T + 3) & 63;

    // P1: MMA T.mh0 [aX,bX]; window-read A-h1(T)->aY
    STAGE(0, 0, 0, P0);  // A-h0(T+2): last read prev-P4 window (POST between)
    STAGE(0, 1, 0, P0);  // B-h0(T+2): last read prev-P4 window
    WIN_OPEN();
    READ_A(0, 1, aY);
    MMA_H(aX, bX, 0);
    WIN_CLOSE();

    // P2: MMA T.mh1 [aY,bX]; drain T+1; window-read T+1 operands
    asm volatile("s_waitcnt vmcnt(4)" ::: "memory");  // drains prev P3+P4 = T+1
    STAGE(0, 0, 1, P0);  // A-h1(T+2): last read P1 window (POST between)
    STAGE(0, 1, 1, P0);  // B-h1(T+2): last read prev-P4 window
    __builtin_amdgcn_s_barrier();  // collective: T+1 fully in LDS
    WIN_OPEN();
    READ_A(1, 0, aX);
    READ_B(1, bY);
    MMA_H(aY, bX, 1);
    WIN_CLOSE();

    // P3: MMA T+1.mh0 [aX,bY]; window-read A-h1(T+1)->aY
    STAGE(1, 0, 0, P1t);  // A-h0(T+3): last read P2 window (POST between)
    STAGE(1, 1, 0, P1t);  // B-h0(T+3): last read P2 window
    WIN_OPEN();
    READ_A(1, 1, aY);
    MMA_H(aX, bY, 0);
    WIN_CLOSE();

    // P4: MMA T+1.mh1 [aY,bY]; drain T+2; window-read T+2 operands
    asm volatile("s_waitcnt vmcnt(4)" ::: "memory");  // drains P1+P2 = T+2
    STAGE(1, 0, 1, P1t);  // A-h1(T+3): last read P3 window (POST between)
    STAGE(1, 1, 1, P1t);  // B-h1(T+3): last read P2 window
    __builtin_amdgcn_s_barrier();  // collective: T+2 fully in LDS
    WIN_OPEN();
    READ_A(0, 0, aX);
    READ_B(0, bX);
    MMA_H(aY, bY, 1);
    WIN_CLOSE();
  }

  // ---- epilogue: C/D layout col=lane&15 (n), row=(lane>>4)*4+reg (m)
  // acc[mf][nf]: m = m0 + (mf>>2)*128 + wr*64 + (mf&3)*16 + h4 + r
  const int h4 = hq * 4;
  float bv[4];
#pragma unroll
  for (int nf = 0; nf < 4; ++nf) bv[nf] = bias[n0 + wc * 64 + nf * 16 + fr];
#pragma unroll
  for (int mf = 0; mf < 8; ++mf) {
    const int m = m0 + (mf >> 2) * 128 + wr * 64 + (mf & 3) * 16 + h4;
#pragma unroll
    for (int nf = 0; nf < 4; ++nf) {
      const int n = n0 + wc * 64 + nf * 16 + fr;
      float* o = out + (size_t)m * OUT_F + n;
#pragma unroll
      for (int r = 0; r < 4; ++r) o[(size_t)r * OUT_F] = acc[mf][nf][r] + bv[nf];
    }
  }
}

// ---------------------------------------------------------------------------
extern "C" void kernel_launch(void* const* d_in, const int* in_sizes, int n_in,
                              void* d_out, int out_size, void* d_ws,
                              size_t ws_size, hipStream_t stream) {
  const float* x = (const float*)d_in[0];
  const int* qweight = (const int*)d_in[1];
  const int* qzeros = (const int*)d_in[2];
  const float* scales = (const float*)d_in[3];
  const float* bias = (const float*)d_in[4];
  float* out = (float*)d_out;

  __hip_bfloat16* xb = (__hip_bfloat16*)d_ws;       // 64 MiB
  __hip_bfloat16* wt = xb + (size_t)TOKENS * IN_F;  // +32 MiB

  // opt-in to 128 KiB dynamic LDS (idempotent; capture-safe)
  (void)hipFuncSetAttribute(reinterpret_cast<const void*>(&k_gemm256),
                            hipFuncAttributeMaxDynamicSharedMemorySize, 131072);

  k_convert_x<<<2048, 256, 0, stream>>>(x, xb);
  k_dequant<<<1024, 256, 0, stream>>>(qweight, qzeros, scales, wt);
  k_gemm256<<<(TOKENS / 256) * (OUT_F / 256), 512, 131072, stream>>>(xb, wt,
                                                                     bias, out);
}

// Round 8
// 278.263 us; speedup vs baseline: 1.0101x; 1.0101x over previous
//
#include <hip/hip_runtime.h>
#include <hip/hip_bf16.h>
#include <stdint.h>

#define TOKENS 8192
#define IN_F   4096
#define OUT_F  4096
#define GROUP  128

typedef __attribute__((ext_vector_type(8))) short short8;
typedef __attribute__((ext_vector_type(4))) float f32x4;

// ---------------------------------------------------------------------------
// Kernel 1: convert x fp32 -> bf16 (workspace). 8 floats / thread-item.
// ---------------------------------------------------------------------------
__global__ void k_convert_x(const float* __restrict__ x,
                            __hip_bfloat16* __restrict__ xb) {
  const int64_t total = (int64_t)TOKENS * IN_F / 8;
  const int64_t stride = (int64_t)gridDim.x * blockDim.x;
  for (int64_t i = (int64_t)blockIdx.x * blockDim.x + threadIdx.x; i < total;
       i += stride) {
    const float4* p = reinterpret_cast<const float4*>(x) + i * 2;
    float4 a = p[0];
    float4 b = p[1];
    union {
      short8 v;
      __hip_bfloat16 h[8];
    } r;
    r.h[0] = __float2bfloat16(a.x);
    r.h[1] = __float2bfloat16(a.y);
    r.h[2] = __float2bfloat16(a.z);
    r.h[3] = __float2bfloat16(a.w);
    r.h[4] = __float2bfloat16(b.x);
    r.h[5] = __float2bfloat16(b.y);
    r.h[6] = __float2bfloat16(b.z);
    r.h[7] = __float2bfloat16(b.w);
    reinterpret_cast<short8*>(xb)[i] = r.v;
  }
}

// ---------------------------------------------------------------------------
// Kernel 2: dequantize qweight -> W^T bf16 [OUT_F][IN_F] (workspace).
// ---------------------------------------------------------------------------
__global__ void k_dequant(const int* __restrict__ qweight,
                          const int* __restrict__ qzeros,
                          const float* __restrict__ scales,
                          __hip_bfloat16* __restrict__ wt) {
  __shared__ __align__(16) __hip_bfloat16 sW[256][72];  // [n][k], +8 pad
  const int nt = blockIdx.x & 15;   // 16 n-tiles
  const int kt = blockIdx.x >> 4;   // 64 k-tiles
  const int n0 = nt * 256;
  const int k0 = kt * 64;           // multiple of 64 -> single group
  const int g = k0 / GROUP;
  const int t = threadIdx.x;
  const int n = n0 + t;

  const float s = scales[(size_t)g * OUT_F + n];
  const unsigned zw =
      ((const unsigned*)qzeros)[(size_t)g * (OUT_F / 8) + (n >> 3)];
  const float z = (float)((zw >> ((n & 7) * 4)) & 15u);
  const float sz = s * z;
  const int kw0 = k0 >> 3;
#pragma unroll
  for (int kw = 0; kw < 8; ++kw) {
    const unsigned w = ((const unsigned*)qweight)[(size_t)(kw0 + kw) * OUT_F + n];
#pragma unroll
    for (int j = 0; j < 8; ++j) {
      const float q = (float)((w >> (4 * j)) & 15u);
      sW[t][kw * 8 + j] = __float2bfloat16(s * q - sz);
    }
  }
  __syncthreads();
#pragma unroll
  for (int pass = 0; pass < 8; ++pass) {
    const int row = pass * 32 + (t >> 3);
    const int kc = t & 7;
    short8 v = *reinterpret_cast<const short8*>(&sW[row][kc * 8]);
    *reinterpret_cast<short8*>(wt + (size_t)(n0 + row) * IN_F + k0 + kc * 8) = v;
  }
}

// ---------------------------------------------------------------------------
// Kernel 3: 256x256 bf16 MFMA GEMM, 4-phase half-tile schedule.
// Round-7 change (single variable): MMA_H reordered kk-OUTERMOST so the
// two MFMAs accumulating into the same acc register are 16 instructions
// apart (dep distance ~310cy > MFMA latency) instead of adjacent.
// Everything else identical to round 7.
// ---------------------------------------------------------------------------
__device__ inline void gload_lds16(const void* g, void* l) {
  __builtin_amdgcn_global_load_lds(
      (const __attribute__((address_space(1))) void*)g,
      (__attribute__((address_space(3))) void*)l, 16, 0, 0);
}

// buf: 0/1, matsel: 0=A 1=B, half: 0/1 (rows half*128..+127), tile: k-tile
#define STAGE(buf, matsel, half, tile)                                        \
  do {                                                                        \
    const char* gb_ = (matsel) ? Bg : Ag;                                     \
    const int lm_ = (buf)*65536 + (matsel)*32768 + (half)*16384;              \
    _Pragma("unroll") for (int r_ = 0; r_ < 2; ++r_) {                        \
      gload_lds16(gb_ + (size_t)(half)*1048576 + goff[r_] +                   \
                      (size_t)(tile)*128,                                     \
                  smem + lm_ + ldsoff[r_]);                                   \
    }                                                                         \
  } while (0)

// A-frag read: m-half mh rows mh*128 + wr*64 + mfl*16 + fr -> dst[4][2]
#define READ_A(buf, mh, dst)                                                  \
  do {                                                                        \
    _Pragma("unroll") for (int mfl_ = 0; mfl_ < 4; ++mfl_) {                  \
      const int row_ = (mh)*128 + wr * 64 + mfl_ * 16 + fr;                   \
      const char* p_ = smem + (buf)*65536 + row_ * 128;                       \
      dst[mfl_][0] = *reinterpret_cast<const short8*>(p_ + csw0);             \
      dst[mfl_][1] = *reinterpret_cast<const short8*>(p_ + csw1);             \
    }                                                                         \
  } while (0)

// B-frag read: this wave's 64 n-rows (wc*64..+63) -> dst[4][2]
#define READ_B(buf, dst)                                                      \
  do {                                                                        \
    _Pragma("unroll") for (int nfl_ = 0; nfl_ < 4; ++nfl_) {                  \
      const int row_ = wc * 64 + nfl_ * 16 + fr;                              \
      const char* p_ = smem + (buf)*65536 + 32768 + row_ * 128;               \
      dst[nfl_][0] = *reinterpret_cast<const short8*>(p_ + csw0);             \
      dst[nfl_][1] = *reinterpret_cast<const short8*>(p_ + csw1);             \
    }                                                                         \
  } while (0)

// 32 MFMA: kk-OUTER ordering — 16 independent MFMAs between the two
// accumulations into any given acc register.
#define MMA_H(aset, bset, mh)                                                 \
  do {                                                                        \
    _Pragma("unroll") for (int kk_ = 0; kk_ < 2; ++kk_)                       \
        _Pragma("unroll") for (int mfl_ = 0; mfl_ < 4; ++mfl_)                \
            _Pragma("unroll") for (int nfl_ = 0; nfl_ < 4; ++nfl_) {          \
      const int mf_ = (mh)*4 + mfl_;                                          \
      acc[mf_][nfl_] = __builtin_amdgcn_mfma_f32_16x16x32_bf16(               \
          aset[mfl_][kk_], bset[nfl_][kk_], acc[mf_][nfl_], 0, 0, 0);         \
    }                                                                         \
  } while (0)

#define WIN_OPEN()                                                            \
  asm volatile("s_waitcnt lgkmcnt(0)" ::: "memory");                          \
  __builtin_amdgcn_sched_barrier(0);                                          \
  __builtin_amdgcn_s_setprio(1)

#define WIN_CLOSE()                                                           \
  __builtin_amdgcn_s_setprio(0);                                              \
  __builtin_amdgcn_sched_barrier(0);                                          \
  __builtin_amdgcn_s_barrier()

__global__ __launch_bounds__(512, 2) void k_gemm256(
    const __hip_bfloat16* __restrict__ xb,  // [TOKENS][IN_F]
    const __hip_bfloat16* __restrict__ wt,  // [OUT_F][IN_F]
    const float* __restrict__ bias,         // [OUT_F]
    float* __restrict__ out) {              // [TOKENS][OUT_F]
  extern __shared__ __align__(16) char smem[];  // 131072 B

  // 2D XCD chunking (bijective): XCD x gets 2bm x 16bn per round.
  const int bidx = blockIdx.x;
  const int xcd = bidx & 7;
  const int slot = bidx >> 3;          // 0..63
  const int rnd = slot >> 5;           // 0/1
  const int jj = slot & 31;
  const int bm = rnd * 16 + xcd * 2 + (jj >> 4);  // 0..31
  const int bn = jj & 15;                          // 0..15
  const int m0 = bm * 256;
  const int n0 = bn * 256;

  const int t = threadIdx.x;
  const int lane = t & 63;
  const int wid = t >> 6;       // 8 waves
  const int wr = wid >> 2;      // 2 (M): 64-row sub-block within m-half
  const int wc = wid & 3;       // 4 (N)
  const int fr = lane & 15;
  const int hq = lane >> 4;     // 0..3, k-quarter

  // swizzled ds_read chunk byte offsets (row&7 == fr&7 for all frag rows)
  const int csw0 = ((hq ^ (fr & 7))) * 16;        // kk=0
  const int csw1 = ((hq ^ (fr & 7)) ^ 4) * 16;    // kk=1

  // staging per-thread constants: round r covers chunk c = r*512 + t
  int goff[2], ldsoff[2];
#pragma unroll
  for (int r = 0; r < 2; ++r) {
    const int srow = r * 64 + wid * 8 + (lane >> 3);        // 0..127
    const int schunk = (lane & 7) ^ (srow & 7);             // inverse swizzle
    goff[r] = srow * (IN_F * 2) + schunk * 16;
    ldsoff[r] = (r * 512 + wid * 64) * 16;                  // wave-uniform
  }

  const char* Ag = (const char*)(xb + (size_t)m0 * IN_F);
  const char* Bg = (const char*)(wt + (size_t)n0 * IN_F);

  f32x4 acc[8][4];
#pragma unroll
  for (int i = 0; i < 8; ++i)
#pragma unroll
    for (int j2 = 0; j2 < 4; ++j2) acc[i][j2] = (f32x4){0.f, 0.f, 0.f, 0.f};

  short8 aX[4][2], aY[4][2];  // A frags: mh0 / mh1
  short8 bX[4][2], bY[4][2];  // B frags: even tile / odd tile

  // ---- prologue: stage tile0 (buf0) then tile1 (buf1); drain tile0.
  STAGE(0, 0, 0, 0);
  STAGE(0, 1, 0, 0);
  STAGE(0, 0, 1, 0);
  STAGE(0, 1, 1, 0);
  STAGE(1, 0, 0, 1);
  STAGE(1, 1, 0, 1);
  STAGE(1, 0, 1, 1);
  STAGE(1, 1, 1, 1);
  asm volatile("s_waitcnt vmcnt(8)" ::: "memory");  // tile0 landed
  __builtin_amdgcn_s_barrier();
  READ_A(0, 0, aX);  // T0 mh0 operands (drained by P1's lgkmcnt)
  READ_B(0, bX);     // B(T0)

  // ---- main loop: tiles T=2it (buf0), T+1 (buf1); 4 half-tile phases.
  for (int it = 0; it < IN_F / 128; ++it) {
    const int T = 2 * it;
    const int P0 = (T + 2) & 63;
    const int P1t = (T + 3) & 63;

    // P1: MMA T.mh0 [aX,bX]; window-read A-h1(T)->aY
    STAGE(0, 0, 0, P0);  // A-h0(T+2): last read prev-P4 window (POST between)
    STAGE(0, 1, 0, P0);  // B-h0(T+2): last read prev-P4 window
    WIN_OPEN();
    READ_A(0, 1, aY);
    MMA_H(aX, bX, 0);
    WIN_CLOSE();

    // P2: MMA T.mh1 [aY,bX]; drain T+1; window-read T+1 operands
    asm volatile("s_waitcnt vmcnt(4)" ::: "memory");  // drains prev P3+P4 = T+1
    STAGE(0, 0, 1, P0);  // A-h1(T+2): last read P1 window (POST between)
    STAGE(0, 1, 1, P0);  // B-h1(T+2): last read prev-P4 window
    __builtin_amdgcn_s_barrier();  // collective: T+1 fully in LDS
    WIN_OPEN();
    READ_A(1, 0, aX);
    READ_B(1, bY);
    MMA_H(aY, bX, 1);
    WIN_CLOSE();

    // P3: MMA T+1.mh0 [aX,bY]; window-read A-h1(T+1)->aY
    STAGE(1, 0, 0, P1t);  // A-h0(T+3): last read P2 window (POST between)
    STAGE(1, 1, 0, P1t);  // B-h0(T+3): last read P2 window
    WIN_OPEN();
    READ_A(1, 1, aY);
    MMA_H(aX, bY, 0);
    WIN_CLOSE();

    // P4: MMA T+1.mh1 [aY,bY]; drain T+2; window-read T+2 operands
    asm volatile("s_waitcnt vmcnt(4)" ::: "memory");  // drains P1+P2 = T+2
    STAGE(1, 0, 1, P1t);  // A-h1(T+3): last read P3 window (POST between)
    STAGE(1, 1, 1, P1t);  // B-h1(T+3): last read P2 window
    __builtin_amdgcn_s_barrier();  // collective: T+2 fully in LDS
    WIN_OPEN();
    READ_A(0, 0, aX);
    READ_B(0, bX);
    MMA_H(aY, bY, 1);
    WIN_CLOSE();
  }

  // ---- epilogue: C/D layout col=lane&15 (n), row=(lane>>4)*4+reg (m)
  // acc[mf][nf]: m = m0 + (mf>>2)*128 + wr*64 + (mf&3)*16 + h4 + r
  const int h4 = hq * 4;
  float bv[4];
#pragma unroll
  for (int nf = 0; nf < 4; ++nf) bv[nf] = bias[n0 + wc * 64 + nf * 16 + fr];
#pragma unroll
  for (int mf = 0; mf < 8; ++mf) {
    const int m = m0 + (mf >> 2) * 128 + wr * 64 + (mf & 3) * 16 + h4;
#pragma unroll
    for (int nf = 0; nf < 4; ++nf) {
      const int n = n0 + wc * 64 + nf * 16 + fr;
      float* o = out + (size_t)m * OUT_F + n;
#pragma unroll
      for (int r = 0; r < 4; ++r) o[(size_t)r * OUT_F] = acc[mf][nf][r] + bv[nf];
    }
  }
}

// ---------------------------------------------------------------------------
extern "C" void kernel_launch(void* const* d_in, const int* in_sizes, int n_in,
                              void* d_out, int out_size, void* d_ws,
                              size_t ws_size, hipStream_t stream) {
  const float* x = (const float*)d_in[0];
  const int* qweight = (const int*)d_in[1];
  const int* qzeros = (const int*)d_in[2];
  const float* scales = (const float*)d_in[3];
  const float* bias = (const float*)d_in[4];
  float* out = (float*)d_out;

  __hip_bfloat16* xb = (__hip_bfloat16*)d_ws;       // 64 MiB
  __hip_bfloat16* wt = xb + (size_t)TOKENS * IN_F;  // +32 MiB

  // opt-in to 128 KiB dynamic LDS (idempotent; capture-safe)
  (void)hipFuncSetAttribute(reinterpret_cast<const void*>(&k_gemm256),
                            hipFuncAttributeMaxDynamicSharedMemorySize, 131072);

  k_convert_x<<<2048, 256, 0, stream>>>(x, xb);
  k_dequant<<<1024, 256, 0, stream>>>(qweight, qzeros, scales, wt);
  k_gemm256<<<(TOKENS / 256) * (OUT_F / 256), 512, 131072, stream>>>(xb, wt,
                                                                     bias, out);
}

// Round 9
// 230.831 us; speedup vs baseline: 1.2176x; 1.2055x over previous
//
#include <hip/hip_runtime.h>
#include <hip/hip_bf16.h>
#include <stdint.h>

#define TOKENS 8192
#define IN_F   4096
#define OUT_F  4096
#define GROUP  128

typedef __attribute__((ext_vector_type(4))) int   i32x4;
typedef __attribute__((ext_vector_type(4))) float f32x4;

// ---------------------------------------------------------------------------
// Kernel 1: quantize x rows to int8 with per-token scale. out = xs[m]*xq.
// ---------------------------------------------------------------------------
__global__ __launch_bounds__(256) void k_quant_x(const float* __restrict__ x,
                                                 int8_t* __restrict__ xq,
                                                 float* __restrict__ xs) {
  const int row = blockIdx.x;
  const int t = threadIdx.x;
  const float4* xr = (const float4*)(x + (size_t)row * IN_F) + t * 4;
  float f[16];
  *(float4*)&f[0] = xr[0];
  *(float4*)&f[4] = xr[1];
  *(float4*)&f[8] = xr[2];
  *(float4*)&f[12] = xr[3];
  float am = 0.f;
#pragma unroll
  for (int j = 0; j < 16; ++j) am = fmaxf(am, fabsf(f[j]));
#pragma unroll
  for (int off = 32; off; off >>= 1) am = fmaxf(am, __shfl_xor(am, off));
  __shared__ float red[4];
  if ((t & 63) == 0) red[t >> 6] = am;
  __syncthreads();
  am = fmaxf(fmaxf(red[0], red[1]), fmaxf(red[2], red[3]));
  am = fmaxf(am, 1e-8f);
  const float inv = 127.f / am;
  if (t == 0) xs[row] = am / 127.f;
  union {
    i32x4 v;
    int8_t c[16];
  } u;
#pragma unroll
  for (int j = 0; j < 16; ++j) u.c[j] = (int8_t)__float2int_rn(f[j] * inv);
  ((i32x4*)(xq + (size_t)row * IN_F))[t] = u.v;
}

// ---------------------------------------------------------------------------
// Kernel 2: unpack weights -> W'^T int8 [OUT_F][IN_F], w' = w - z (exact).
// ---------------------------------------------------------------------------
__global__ __launch_bounds__(256) void k_dequant_w8(
    const int* __restrict__ qweight, const int* __restrict__ qzeros,
    int8_t* __restrict__ wq) {
  __shared__ __align__(16) int8_t sW[256][80];  // [n][k 64 + 16 pad]
  const int nt = blockIdx.x & 15;   // 16 n-tiles
  const int kt = blockIdx.x >> 4;   // 64 k-tiles
  const int n0 = nt * 256;
  const int k0 = kt * 64;
  const int g = k0 / GROUP;
  const int t = threadIdx.x;
  const int n = n0 + t;

  const unsigned zw =
      ((const unsigned*)qzeros)[(size_t)g * (OUT_F / 8) + (n >> 3)];
  const int z = (int)((zw >> ((n & 7) * 4)) & 15u);
  const int kw0 = k0 >> 3;
#pragma unroll
  for (int kw = 0; kw < 8; ++kw) {
    const unsigned w = ((const unsigned*)qweight)[(size_t)(kw0 + kw) * OUT_F + n];
#pragma unroll
    for (int j = 0; j < 8; ++j) {
      const int q = (int)((w >> (4 * j)) & 15u);
      sW[t][kw * 8 + j] = (int8_t)(q - z);
    }
  }
  __syncthreads();
#pragma unroll
  for (int pass = 0; pass < 4; ++pass) {
    const int row = pass * 64 + (t >> 2);
    const int kc = t & 3;
    i32x4 v = *(const i32x4*)&sW[row][kc * 16];
    *(i32x4*)(wq + (size_t)(n0 + row) * IN_F + k0 + kc * 16) = v;
  }
}

// ---------------------------------------------------------------------------
// Kernel 3: int8 MFMA GEMM with per-group (=per-K-tile, 128) dequant.
// Block 256m x 128n, 512 thr = 8 waves (4M x 2N), wave tile 64x64.
// LDS: 2 bufs x (A 32KB + B 16KB) = 96KB + s-table 8KB = 104KB.
// Tile = [rows][128 B] int8 = 8x16B chunks/row -> same swizzle as bf16 ver.
// 4 phases / 2 tiles; iacc built with C=0 on kk0; deq of each n-half runs
// in the next phase (disjoint iacc regs); s read 1 phase ahead from LDS.
// vmcnt(4) at P2/P4 before own stages drains exactly the tile read next.
// ---------------------------------------------------------------------------
__device__ inline void gload_lds16(const void* g, void* l) {
  __builtin_amdgcn_global_load_lds(
      (const __attribute__((address_space(1))) void*)g,
      (__attribute__((address_space(3))) void*)l, 16, 0, 0);
}

#define STAGE_A(buf, half, tile)                                              \
  do {                                                                        \
    _Pragma("unroll") for (int r_ = 0; r_ < 2; ++r_) {                        \
      gload_lds16(Ag + (size_t)(half) * (128 * IN_F) + goff[r_] +             \
                      (size_t)((tile) & 31) * 128,                            \
                  smem + (buf)*49152 + (half)*16384 + ldsoff[r_]);            \
    }                                                                         \
  } while (0)

#define STAGE_B(buf, tile)                                                    \
  do {                                                                        \
    _Pragma("unroll") for (int r_ = 0; r_ < 2; ++r_) {                        \
      gload_lds16(Bg + goff[r_] + (size_t)((tile) & 31) * 128,                \
                  smem + (buf)*49152 + 32768 + ldsoff[r_]);                   \
    }                                                                         \
  } while (0)

#define READ_A(buf, dst)                                                      \
  do {                                                                        \
    _Pragma("unroll") for (int mfl_ = 0; mfl_ < 4; ++mfl_) {                  \
      const int row_ = wr * 64 + mfl_ * 16 + fr;                              \
      const char* p_ = smem + (buf)*49152 + row_ * 128;                       \
      dst[mfl_][0] = *reinterpret_cast<const i32x4*>(p_ + csw0);              \
      dst[mfl_][1] = *reinterpret_cast<const i32x4*>(p_ + csw1);              \
    }                                                                         \
  } while (0)

#define READ_B(buf, nh, dst)                                                  \
  do {                                                                        \
    _Pragma("unroll") for (int nfl_ = 0; nfl_ < 2; ++nfl_) {                  \
      const int row_ = wc * 64 + ((nh)*2 + nfl_) * 16 + fr;                   \
      const char* p_ = smem + (buf)*49152 + 32768 + row_ * 128;               \
      dst[nfl_][0] = *reinterpret_cast<const i32x4*>(p_ + csw0);              \
      dst[nfl_][1] = *reinterpret_cast<const i32x4*>(p_ + csw1);              \
    }                                                                         \
  } while (0)

// 4 u16 reads of s[tile] for this wave's 4 n-frag columns
#define READ_S(tile, dst)                                                     \
  do {                                                                        \
    _Pragma("unroll") for (int nf_ = 0; nf_ < 4; ++nf_) {                     \
      dst[nf_] = *reinterpret_cast<const unsigned short*>(                    \
          smem + 98304 +                                                      \
          (((tile)&31) * 128 + wc * 64 + nf_ * 16 + fr) * 2);                 \
    }                                                                         \
  } while (0)

// 16 MFMA: kk0 with C=0 (fresh group), then kk1 accumulating.
#define MMA_NH(aset, bset, nh)                                                \
  do {                                                                        \
    _Pragma("unroll") for (int mfl_ = 0; mfl_ < 4; ++mfl_)                    \
        _Pragma("unroll") for (int nfl_ = 0; nfl_ < 2; ++nfl_) {              \
      iacc[mfl_][(nh)*2 + nfl_] = __builtin_amdgcn_mfma_i32_16x16x64_i8(      \
          aset[mfl_][0], bset[nfl_][0], zero4, 0, 0, 0);                      \
    }                                                                         \
    _Pragma("unroll") for (int mfl_ = 0; mfl_ < 4; ++mfl_)                    \
        _Pragma("unroll") for (int nfl_ = 0; nfl_ < 2; ++nfl_) {              \
      iacc[mfl_][(nh)*2 + nfl_] = __builtin_amdgcn_mfma_i32_16x16x64_i8(      \
          aset[mfl_][1], bset[nfl_][1], iacc[mfl_][(nh)*2 + nfl_], 0, 0, 0);  \
    }                                                                         \
  } while (0)

#define DEQ(nh, sreg)                                                         \
  do {                                                                        \
    _Pragma("unroll") for (int nfl_ = 0; nfl_ < 2; ++nfl_) {                  \
      const int nf_ = (nh)*2 + nfl_;                                          \
      const float sv_ = __uint_as_float((unsigned)(sreg)[nf_] << 16);         \
      _Pragma("unroll") for (int mfl_ = 0; mfl_ < 4; ++mfl_)                  \
          _Pragma("unroll") for (int r_ = 0; r_ < 4; ++r_) {                  \
        facc[mfl_][nf_][r_] += sv_ * (float)iacc[mfl_][nf_][r_];              \
      }                                                                       \
    }                                                                         \
  } while (0)

#define WIN_OPEN()                                                            \
  asm volatile("s_waitcnt lgkmcnt(0)" ::: "memory");                          \
  __builtin_amdgcn_sched_barrier(0);                                          \
  __builtin_amdgcn_s_setprio(1)

#define WIN_CLOSE()                                                           \
  __builtin_amdgcn_s_setprio(0);                                              \
  __builtin_amdgcn_sched_barrier(0);                                          \
  __builtin_amdgcn_s_barrier()

__global__ __launch_bounds__(512, 2) void k_gemm_i8(
    const int8_t* __restrict__ xq,   // [TOKENS][IN_F]
    const int8_t* __restrict__ wq,   // [OUT_F][IN_F]
    const float* __restrict__ scales,// [32][OUT_F]
    const float* __restrict__ xs,    // [TOKENS]
    const float* __restrict__ bias,  // [OUT_F]
    float* __restrict__ out) {       // [TOKENS][OUT_F]
  extern __shared__ __align__(16) char smem[];  // 106496 B

  // 2D XCD chunking: xcd gets 4bm x 32bn; 32 CUs share one A-panel at a time
  const int bidx = blockIdx.x;
  const int xcd = bidx & 7;
  const int slot = bidx >> 3;               // 0..127
  const int bm = xcd * 4 + (slot >> 5);     // 0..31
  const int bn = slot & 31;                 // 0..31
  const int m0 = bm * 256;
  const int n0 = bn * 128;

  const int t = threadIdx.x;
  const int lane = t & 63;
  const int wid = t >> 6;    // 8 waves
  const int wr = wid >> 1;   // 4 (M)
  const int wc = wid & 1;    // 2 (N)
  const int fr = lane & 15;
  const int hq = lane >> 4;  // k-quarter (16 int8 each)

  const int csw0 = (hq ^ (fr & 7)) * 16;
  const int csw1 = ((hq ^ (fr & 7)) ^ 4) * 16;

  int goff[2], ldsoff[2];
#pragma unroll
  for (int r = 0; r < 2; ++r) {
    const int srow = r * 64 + wid * 8 + (lane >> 3);  // 0..127
    const int schunk = (lane & 7) ^ (srow & 7);
    goff[r] = srow * IN_F + schunk * 16;              // int8: pitch 4096 B
    ldsoff[r] = (r * 512 + wid * 64) * 16;            // wave-uniform
  }

  const char* Ag = (const char*)(xq + (size_t)m0 * IN_F);
  const char* Bg = (const char*)(wq + (size_t)n0 * IN_F);

  // ---- fill s-table: [32 g][128 cols] bf16 at smem+98304
  {
#pragma unroll
    for (int j = 0; j < 8; ++j) {
      const int idx = t * 8 + j;            // 0..4095
      const int g = idx >> 7, c = idx & 127;
      const float sv = scales[(size_t)g * OUT_F + n0 + c];
      *reinterpret_cast<unsigned short*>(smem + 98304 + idx * 2) =
          (unsigned short)(__bfloat16_as_ushort(__float2bfloat16(sv)));
    }
  }
  __builtin_amdgcn_sched_barrier(0);
  asm volatile("s_waitcnt vmcnt(0) lgkmcnt(0)" ::: "memory");
  __builtin_amdgcn_s_barrier();

  f32x4 facc[4][4];
#pragma unroll
  for (int i = 0; i < 4; ++i)
#pragma unroll
    for (int j = 0; j < 4; ++j) facc[i][j] = (f32x4){0.f, 0.f, 0.f, 0.f};
  i32x4 iacc[4][4];
  const i32x4 zero4 = {0, 0, 0, 0};

  i32x4 aX[4][2], aY[4][2];
  i32x4 bX[2][2], bY[2][2], bX2[2][2], bY2[2][2];
  unsigned short sE[4], sO[4];

  // ---- prologue: stage tile0 (buf0: A h0,h1 + B) then tile1 (buf1)
  STAGE_A(0, 0, 0);
  STAGE_A(0, 1, 0);
  STAGE_B(0, 0);
  STAGE_A(1, 0, 1);
  STAGE_A(1, 1, 1);
  STAGE_B(1, 1);
  asm volatile("s_waitcnt vmcnt(6)" ::: "memory");  // tile0 landed
  __builtin_amdgcn_s_barrier();
  READ_A(0, aX);
  READ_B(0, 0, bX);

  // ---- main loop: tiles T=2it (buf0), T+1 (buf1); groups == tiles.
#pragma unroll 1
  for (int it = 0; it < 16; ++it) {
    const int T = 2 * it;

    // P1: MMA T.nh0 [aX,bX]; read bY=B(T).nh1, sE=s[T]; deq (T-1).nh1 [sO]
    STAGE_A(0, 0, T + 2);
    STAGE_A(0, 1, T + 2);
    WIN_OPEN();
    MMA_NH(aX, bX, 0);
    READ_B(0, 1, bY);
    READ_S(T, sE);
    if (it) DEQ(1, sO);
    WIN_CLOSE();

    // P2: drain tile T+1; MMA T.nh1 [aX,bY]; read aY,bX2 of T+1; deq T.nh0
    asm volatile("s_waitcnt vmcnt(4)" ::: "memory");
    STAGE_B(0, T + 2);
    __builtin_amdgcn_s_barrier();  // publish T+1
    WIN_OPEN();
    MMA_NH(aX, bY, 1);
    READ_A(1, aY);
    READ_B(1, 0, bX2);
    DEQ(0, sE);
    WIN_CLOSE();

    // P3: MMA T+1.nh0 [aY,bX2]; read bY2, sO=s[T+1]; deq T.nh1 [sE]
    STAGE_A(1, 0, T + 3);
    STAGE_A(1, 1, T + 3);
    WIN_OPEN();
    MMA_NH(aY, bX2, 0);
    READ_B(1, 1, bY2);
    READ_S(T + 1, sO);
    DEQ(1, sE);
    WIN_CLOSE();

    // P4: drain tile T+2; MMA T+1.nh1 [aY,bY2]; read aX,bX of T+2; deq T+1.nh0
    asm volatile("s_waitcnt vmcnt(4)" ::: "memory");
    STAGE_B(1, T + 3);
    __builtin_amdgcn_s_barrier();  // publish T+2
    WIN_OPEN();
    MMA_NH(aY, bY2, 1);
    READ_A(0, aX);
    READ_B(0, 0, bX);
    DEQ(0, sO);
    WIN_CLOSE();
  }
  DEQ(1, sO);  // tile 31 nh1

  // ---- epilogue: out = xs[m]*facc + bias[n]
  const int h4 = hq * 4;
  float bv[4];
#pragma unroll
  for (int nf = 0; nf < 4; ++nf) bv[nf] = bias[n0 + wc * 64 + nf * 16 + fr];
#pragma unroll
  for (int mf = 0; mf < 4; ++mf) {
#pragma unroll
    for (int r = 0; r < 4; ++r) {
      const int m = m0 + wr * 64 + mf * 16 + h4 + r;
      const float xsv = xs[m];
      float* o = out + (size_t)m * OUT_F + n0;
#pragma unroll
      for (int nf = 0; nf < 4; ++nf) {
        o[wc * 64 + nf * 16 + fr] = xsv * facc[mf][nf][r] + bv[nf];
      }
    }
  }
}

// ---------------------------------------------------------------------------
extern "C" void kernel_launch(void* const* d_in, const int* in_sizes, int n_in,
                              void* d_out, int out_size, void* d_ws,
                              size_t ws_size, hipStream_t stream) {
  const float* x = (const float*)d_in[0];
  const int* qweight = (const int*)d_in[1];
  const int* qzeros = (const int*)d_in[2];
  const float* scales = (const float*)d_in[3];
  const float* bias = (const float*)d_in[4];
  float* out = (float*)d_out;

  int8_t* xq = (int8_t*)d_ws;                          // 32 MiB
  int8_t* wq = xq + (size_t)TOKENS * IN_F;             // +16 MiB
  float* xs = (float*)(wq + (size_t)OUT_F * IN_F);     // +32 KiB

  (void)hipFuncSetAttribute(reinterpret_cast<const void*>(&k_gemm_i8),
                            hipFuncAttributeMaxDynamicSharedMemorySize, 106496);

  k_quant_x<<<TOKENS, 256, 0, stream>>>(x, xq, xs);
  k_dequant_w8<<<1024, 256, 0, stream>>>(qweight, qzeros, wq);
  k_gemm_i8<<<(TOKENS / 256) * (OUT_F / 128), 512, 106496, stream>>>(
      xq, wq, scales, xs, bias, out);
}